// Round 8
// baseline (392.879 us; speedup 1.0000x reference)
//
#include <hip/hip_runtime.h>

// obj = (99*sum_t ||c_t||^2 + ||sum_t c_t||^2)/100, c_0 = D_F,
// c_{k+1} = E_k = C_F A_F^k B_F - C A^k B, B = eye(256,128), k=0..7.
//
// POWER-DOUBLING dataflow (verified absmax ~0 rounds 5-7):
//   P1: AF2=AF*AF, G1=CF*AF, A2=A*A, H1=C*A (+copies G0=CF, H0=C)
//   P2: AF4=AF2*AF2, [G2;G3]=G[0:256]*AF2, A4, [H2;H3]
//   P3: [G4..G7]=G[0:512]*AF4, [H4..H7]=H[0:512]*A4
//   P4: Ef=G*BF - H[:,:128] ;  F: S1=sum|E|^2, S2=|DF+sumE|^2, SD=|DF|^2.
// Round-7 post-mortem: good per-wave loop but grids of 64-184 full-K blocks
// left the GPU idle (Occupancy 2.1%, 1 wave/SIMD -> exposed LDS latency).
// This revision: SPLIT-K fan-4 with fp32 atomicAdd accumulation into
// canonical fp32 buffers (one 9.7MB memset) -> grids 592/736/640/256 at
// 3 blocks/CU. No bf16 tables: consumers convert fp32->bf16 during LDS
// B-staging (same rounding point -> same numerics class). Inner loop is
// round-7's proven 16x128 tile / 2x4 thread tile / conflict-free layout.

struct Params {
    const float *AFr, *AFi, *Ar, *Ai, *BFr, *BFi, *CFr, *CFi, *Cr, *Ci, *DFr, *DFi;
    float2 *Gf, *Hf, *AF2f, *AF4f, *A2f, *A4f, *Ef;
    float *S1, *S2, *SD; unsigned int *tick; float *out;
};

__device__ __forceinline__ unsigned int pk_bf16(float r, float i) {
    unsigned int u;
    asm("v_cvt_pk_bf16_f32 %0, %1, %2" : "=v"(u) : "v"(r), "v"(i));
    return u;   // low16 = bf16(r), high16 = bf16(i)
}

__device__ __forceinline__ float block_reduce(float v, float* red, int tid) {
    red[tid] = v;
    __syncthreads();
    for (int off = 128; off > 0; off >>= 1) {
        if (tid < off) red[tid] += red[tid + off];
        __syncthreads();
    }
    float r = red[0];
    __syncthreads();
    return r;
}

// one complex MAC against a packed-bf16 word
#define CM(wd, ar, ai, o)                                              \
    { float br_ = __uint_as_float((wd) << 16);                         \
      float bi_ = __uint_as_float((wd) & 0xffff0000u);                 \
      acc[o]     += (ar) * br_ - (ai) * bi_;                           \
      acc[(o)+1] += (ar) * bi_ + (ai) * br_; }

// ---- split-K GEMM: block tile 16 rows x 128 cols at (rg*16, c0), K-range
// [k0, k0+NCH*32). Thread (w=tid>>6, hi=(tid>>5)&1, cc=tid&31) owns rows
// {4w+2hi, +1}, cols {c0+4cc..+3}: acc[16]. Q fp32 (split r/i or float2);
// B fp32 (split r/i or float2), converted to packed bf16 in LDS staging.
template<int NCH, bool QSPLIT, bool BSPLIT>
__device__ __forceinline__ void gemmK(
    const float* __restrict__ Qr_, const float* __restrict__ Qi_,
    const float2* __restrict__ Qf, int Wq,
    const float* __restrict__ Br_, const float* __restrict__ Bi_,
    const float2* __restrict__ Bf, int Wb,
    int c0, int rg, int k0, unsigned int* sBu, float2* sQ, float* acc) {
    const int tid = threadIdx.x;
    const int cc = tid & 31;
    const int r0 = 4 * (tid >> 6) + 2 * ((tid >> 5) & 1);
    #pragma unroll 1
    for (int ch = 0; ch < NCH; ++ch) {
        if (ch) __syncthreads();             // prior chunk's readers done
        const int kb = k0 + ch * 32;
        // B slab: 32 k-rows x 128 cols packed bf16 (u32/complex)
        if constexpr (BSPLIT) {
            #pragma unroll
            for (int j = 0; j < 4; ++j) {
                int slot = tid + j * 256;
                int row = slot >> 5, cq = (slot & 31) << 2;
                int g = (kb + row) * Wb + c0 + cq;
                float4 vr = *(const float4*)&Br_[g];
                float4 vi = *(const float4*)&Bi_[g];
                *(uint4*)&sBu[(row << 7) + cq] = make_uint4(
                    pk_bf16(vr.x, vi.x), pk_bf16(vr.y, vi.y),
                    pk_bf16(vr.z, vi.z), pk_bf16(vr.w, vi.w));
            }
        } else {
            #pragma unroll
            for (int j = 0; j < 8; ++j) {
                int slot = tid + j * 256;
                int row = slot >> 6, c2 = (slot & 63) << 1;
                float4 v = *(const float4*)&Bf[(kb + row) * Wb + c0 + c2];
                *(uint2*)&sBu[(row << 7) + c2] =
                    make_uint2(pk_bf16(v.x, v.y), pk_bf16(v.z, v.w));
            }
        }
        // Q: 16 rows x 32 k (f2), row-major, LDQ=34 f2 (pad: bank spread)
        {
            int row = tid >> 4, k2 = (tid & 15) << 1;
            int gq = (rg * 16 + row) * Wq + kb + k2;
            float4 v;
            if constexpr (QSPLIT) {
                float2 r2 = *(const float2*)&Qr_[gq];
                float2 i2 = *(const float2*)&Qi_[gq];
                v = make_float4(r2.x, i2.x, r2.y, i2.y);
            } else {
                v = *(const float4*)&Qf[gq];
            }
            *(float4*)&sQ[row * 34 + k2] = v;
        }
        __syncthreads();
        #pragma unroll 4
        for (int kk = 0; kk < 32; kk += 2) {
            float4 qa = *(const float4*)&sQ[r0 * 34 + kk];
            float4 qb = *(const float4*)&sQ[(r0 + 1) * 34 + kk];
            uint4 b0 = *(const uint4*)&sBu[(kk << 7) + (cc << 2)];
            uint4 b1 = *(const uint4*)&sBu[((kk + 1) << 7) + (cc << 2)];
            CM(b0.x, qa.x, qa.y, 0)  CM(b0.y, qa.x, qa.y, 2)
            CM(b0.z, qa.x, qa.y, 4)  CM(b0.w, qa.x, qa.y, 6)
            CM(b0.x, qb.x, qb.y, 8)  CM(b0.y, qb.x, qb.y, 10)
            CM(b0.z, qb.x, qb.y, 12) CM(b0.w, qb.x, qb.y, 14)
            CM(b1.x, qa.z, qa.w, 0)  CM(b1.y, qa.z, qa.w, 2)
            CM(b1.z, qa.z, qa.w, 4)  CM(b1.w, qa.z, qa.w, 6)
            CM(b1.x, qb.z, qb.w, 8)  CM(b1.y, qb.z, qb.w, 10)
            CM(b1.z, qb.z, qb.w, 12) CM(b1.w, qb.z, qb.w, 14)
        }
    }
}

// atomic-accumulate one row of 4 complexes (split-K fan-in)
__device__ __forceinline__ void atom_acc(float2* O, int W, int prow, int pc,
                                         const float* a8) {
    float* Of = (float*)O;
    int base = (prow * W + pc) * 2;
    #pragma unroll
    for (int j = 0; j < 8; ++j) atomicAdd(&Of[base + j], a8[j]);
}

#define TMAP const int w = tid >> 6, hi = (tid >> 5) & 1, cc = tid & 31; \
             const int r0 = 4 * w + 2 * hi, pc4 = cc << 2; (void)0

// ---------------- P1 (592): AF2, G1, A2, H1, copies -------------------------
// [0,288): AF2 24rg x 3cs x 4kp   [288,384): G1 8x3x4
// [384,512): A2 16x2x4            [512,576): H1 8x2x4   [576,592): copies
__global__ __launch_bounds__(256, 3)
void p1_kernel(Params P) {
    __shared__ __align__(16) unsigned int sBu[32 * 128];  // 16 KB
    __shared__ __align__(16) float2 sQ[16 * 34];          // 4.25 KB
    const int b = blockIdx.x, tid = threadIdx.x;
    TMAP;
    float acc[16] = {};
    if (b < 288) {
        int rg = b / 12, r = b - 12 * rg, cs = r >> 2, kp = r & 3;
        gemmK<3, true, true>(P.AFr, P.AFi, nullptr, 384, P.AFr, P.AFi, nullptr, 384,
                             cs << 7, rg, kp * 96, sBu, sQ, acc);
        int prow = rg * 16 + r0, pc = (cs << 7) + pc4;
        atom_acc(P.AF2f, 384, prow, pc, acc);  atom_acc(P.AF2f, 384, prow + 1, pc, acc + 8);
    } else if (b < 384) {
        int u = b - 288, rg = u / 12, r = u - 12 * rg, cs = r >> 2, kp = r & 3;
        gemmK<3, true, true>(P.CFr, P.CFi, nullptr, 384, P.AFr, P.AFi, nullptr, 384,
                             cs << 7, rg, kp * 96, sBu, sQ, acc);
        float2* O = P.Gf + 128 * 384;
        int prow = rg * 16 + r0, pc = (cs << 7) + pc4;
        atom_acc(O, 384, prow, pc, acc);       atom_acc(O, 384, prow + 1, pc, acc + 8);
    } else if (b < 512) {
        int u = b - 384, rg = u >> 3, r = u & 7, cs = r >> 2, kp = r & 3;
        gemmK<2, true, true>(P.Ar, P.Ai, nullptr, 256, P.Ar, P.Ai, nullptr, 256,
                             cs << 7, rg, kp * 64, sBu, sQ, acc);
        int prow = rg * 16 + r0, pc = (cs << 7) + pc4;
        atom_acc(P.A2f, 256, prow, pc, acc);   atom_acc(P.A2f, 256, prow + 1, pc, acc + 8);
    } else if (b < 576) {
        int u = b - 512, rg = u >> 3, r = u & 7, cs = r >> 2, kp = r & 3;
        gemmK<2, true, true>(P.Cr, P.Ci, nullptr, 256, P.Ar, P.Ai, nullptr, 256,
                             cs << 7, rg, kp * 64, sBu, sQ, acc);
        float2* O = P.Hf + 128 * 256;
        int prow = rg * 16 + r0, pc = (cs << 7) + pc4;
        atom_acc(O, 256, prow, pc, acc);       atom_acc(O, 256, prow + 1, pc, acc + 8);
    } else {
        for (int i = (b - 576) * 256 + tid; i < 81920; i += 16 * 256) {
            if (i < 49152) P.Gf[i] = make_float2(P.CFr[i], P.CFi[i]);          // G0
            else { int j = i - 49152; P.Hf[j] = make_float2(P.Cr[j], P.Ci[j]); } // H0
        }
    }
}

// ---------------- P2 (736): AF4, [G2;G3], A4, [H2;H3] -----------------------
// [0,288): AF4 24x3x4  [288,480): G23 16x3x4  [480,608): A4 16x2x4
// [608,736): H23 16x2x4
__global__ __launch_bounds__(256, 3)
void p2_kernel(Params P) {
    __shared__ __align__(16) unsigned int sBu[32 * 128];
    __shared__ __align__(16) float2 sQ[16 * 34];
    const int b = blockIdx.x, tid = threadIdx.x;
    TMAP;
    float acc[16] = {};
    if (b < 288) {
        int rg = b / 12, r = b - 12 * rg, cs = r >> 2, kp = r & 3;
        gemmK<3, false, false>(nullptr, nullptr, P.AF2f, 384, nullptr, nullptr, P.AF2f, 384,
                               cs << 7, rg, kp * 96, sBu, sQ, acc);
        int prow = rg * 16 + r0, pc = (cs << 7) + pc4;
        atom_acc(P.AF4f, 384, prow, pc, acc);  atom_acc(P.AF4f, 384, prow + 1, pc, acc + 8);
    } else if (b < 480) {
        int u = b - 288, rg = u / 12, r = u - 12 * rg, cs = r >> 2, kp = r & 3;
        gemmK<3, false, false>(nullptr, nullptr, P.Gf, 384, nullptr, nullptr, P.AF2f, 384,
                               cs << 7, rg, kp * 96, sBu, sQ, acc);
        float2* O = P.Gf + 256 * 384;
        int prow = rg * 16 + r0, pc = (cs << 7) + pc4;
        atom_acc(O, 384, prow, pc, acc);       atom_acc(O, 384, prow + 1, pc, acc + 8);
    } else if (b < 608) {
        int u = b - 480, rg = u >> 3, r = u & 7, cs = r >> 2, kp = r & 3;
        gemmK<2, false, false>(nullptr, nullptr, P.A2f, 256, nullptr, nullptr, P.A2f, 256,
                               cs << 7, rg, kp * 64, sBu, sQ, acc);
        int prow = rg * 16 + r0, pc = (cs << 7) + pc4;
        atom_acc(P.A4f, 256, prow, pc, acc);   atom_acc(P.A4f, 256, prow + 1, pc, acc + 8);
    } else {
        int u = b - 608, rg = u >> 3, r = u & 7, cs = r >> 2, kp = r & 3;
        gemmK<2, false, false>(nullptr, nullptr, P.Hf, 256, nullptr, nullptr, P.A2f, 256,
                               cs << 7, rg, kp * 64, sBu, sQ, acc);
        float2* O = P.Hf + 256 * 256;
        int prow = rg * 16 + r0, pc = (cs << 7) + pc4;
        atom_acc(O, 256, prow, pc, acc);       atom_acc(O, 256, prow + 1, pc, acc + 8);
    }
}

// ---------------- P3 (640): [G4..G7], [H4..H7] ------------------------------
// [0,384): G4567 32x3x4     [384,640): H4567 32x2x4
__global__ __launch_bounds__(256, 3)
void p3_kernel(Params P) {
    __shared__ __align__(16) unsigned int sBu[32 * 128];
    __shared__ __align__(16) float2 sQ[16 * 34];
    const int b = blockIdx.x, tid = threadIdx.x;
    TMAP;
    float acc[16] = {};
    if (b < 384) {
        int rg = b / 12, r = b - 12 * rg, cs = r >> 2, kp = r & 3;
        gemmK<3, false, false>(nullptr, nullptr, P.Gf, 384, nullptr, nullptr, P.AF4f, 384,
                               cs << 7, rg, kp * 96, sBu, sQ, acc);
        float2* O = P.Gf + 512 * 384;
        int prow = rg * 16 + r0, pc = (cs << 7) + pc4;
        atom_acc(O, 384, prow, pc, acc);       atom_acc(O, 384, prow + 1, pc, acc + 8);
    } else {
        int u = b - 384, rg = u >> 3, r = u & 7, cs = r >> 2, kp = r & 3;
        gemmK<2, false, false>(nullptr, nullptr, P.Hf, 256, nullptr, nullptr, P.A4f, 256,
                               cs << 7, rg, kp * 64, sBu, sQ, acc);
        float2* O = P.Hf + 512 * 256;
        int prow = rg * 16 + r0, pc = (cs << 7) + pc4;
        atom_acc(O, 256, prow, pc, acc);       atom_acc(O, 256, prow + 1, pc, acc + 8);
    }
}

// ---------------- P4 (256): Ef = G*BF - H[:,:128] ---------------------------
// rg = b>>2 (0..63: E rows rg*16..+15), kp = b&3 (K-part); part 0 subtracts H.
__global__ __launch_bounds__(256, 3)
void p4_kernel(Params P) {
    __shared__ __align__(16) unsigned int sBu[32 * 128];
    __shared__ __align__(16) float2 sQ[16 * 34];
    const int b = blockIdx.x, tid = threadIdx.x;
    TMAP;
    const int rg = b >> 2, kp = b & 3;
    float acc[16] = {};
    gemmK<3, false, true>(nullptr, nullptr, P.Gf, 384, P.BFr, P.BFi, nullptr, 128,
                          0, rg, kp * 96, sBu, sQ, acc);
    const int prow = rg * 16 + r0;
    if (kp == 0) {
        #pragma unroll
        for (int rr = 0; rr < 2; ++rr) {
            float* a8 = acc + 8 * rr;
            float4 h0 = *(const float4*)&P.Hf[(prow + rr) * 256 + pc4];
            float4 h1 = *(const float4*)&P.Hf[(prow + rr) * 256 + pc4 + 2];
            a8[0] -= h0.x; a8[1] -= h0.y; a8[2] -= h0.z; a8[3] -= h0.w;
            a8[4] -= h1.x; a8[5] -= h1.y; a8[6] -= h1.z; a8[7] -= h1.w;
        }
    }
    atom_acc(P.Ef, 128, prow, pc4, acc);
    atom_acc(P.Ef, 128, prow + 1, pc4, acc + 8);
}

// ---------------- F (64): reductions + ticketed scalar out ------------------
__global__ __launch_bounds__(256)
void fin_kernel(Params P) {
    __shared__ float red[256];
    __shared__ int lastf;
    const int b = blockIdx.x, tid = threadIdx.x;
    const int idx = (b << 8) + tid;            // 0..16383 = p*128 + m
    const int p = idx >> 7, m = idx & 127;
    float dr = P.DFr[idx], di = P.DFi[idx];
    float s1 = 0.f, smr = dr, smi = di;
    #pragma unroll
    for (int k = 0; k < 8; ++k) {
        float2 e = P.Ef[((k << 7) + p) * 128 + m];
        s1 += e.x * e.x + e.y * e.y;
        smr += e.x; smi += e.y;
    }
    float s2 = smr * smr + smi * smi;
    float sd = dr * dr + di * di;
    float t = block_reduce(s1, red, tid);
    if (tid == 0) atomicAdd(P.S1, t);
    t = block_reduce(s2, red, tid);
    if (tid == 0) atomicAdd(P.S2, t);
    t = block_reduce(sd, red, tid);
    if (tid == 0) atomicAdd(P.SD, t);
    __syncthreads();   // drains this block's atomics (vmcnt) before ticket
    if (tid == 0) lastf = (atomicAdd(P.tick, 1u) == 63u) ? 1 : 0;
    __syncthreads();
    if (lastf && tid == 0) {
        float s1g = atomicAdd(P.S1, 0.f);
        float s2g = atomicAdd(P.S2, 0.f);
        float sdg = atomicAdd(P.SD, 0.f);
        P.out[0] = (99.0f * (s1g + sdg) + s2g) / 100.0f;
    }
}

extern "C" void kernel_launch(void* const* d_in, const int* in_sizes, int n_in,
                              void* d_out, int out_size, void* d_ws, size_t ws_size,
                              hipStream_t stream) {
    (void)in_sizes; (void)n_in; (void)out_size; (void)ws_size;
    char* ws = (char*)d_ws;
    Params h;
    h.Cr  = (const float*)d_in[0];
    h.Ci  = (const float*)d_in[1];
    h.Ar  = (const float*)d_in[2];
    h.Ai  = (const float*)d_in[3];
    h.AFr = (const float*)d_in[4];
    h.AFi = (const float*)d_in[5];
    h.BFr = (const float*)d_in[6];
    h.BFi = (const float*)d_in[7];
    h.CFr = (const float*)d_in[8];
    h.CFi = (const float*)d_in[9];
    h.DFr = (const float*)d_in[10];
    h.DFi = (const float*)d_in[11];
    h.Gf   = (float2*)(ws + 0);              // 1024x384 c64 = 3145728
    h.Hf   = (float2*)(ws + 3145728);        // 1024x256 c64 = 2097152 -> 5242880
    h.AF2f = (float2*)(ws + 5242880);        // 384x384 = 1179648 -> 6422528
    h.AF4f = (float2*)(ws + 6422528);        // 1179648 -> 7602176
    h.A2f  = (float2*)(ws + 7602176);        // 256x256 = 524288 -> 8126464
    h.A4f  = (float2*)(ws + 8126464);        // 524288 -> 8650752
    h.Ef   = (float2*)(ws + 8650752);        // 1024x128 = 1048576 -> 9699328
    h.S1   = (float*)(ws + 9699328);
    h.S2   = (float*)(ws + 9699332);
    h.SD   = (float*)(ws + 9699336);
    h.tick = (unsigned int*)(ws + 9699340);
    h.out  = (float*)d_out;

    // zero all atomic-accumulation targets + scalars (9.7 MB ~ 1.5 us)
    hipMemsetAsync(ws, 0, 9699344, stream);
    p1_kernel<<<592, 256, 0, stream>>>(h);
    p2_kernel<<<736, 256, 0, stream>>>(h);
    p3_kernel<<<640, 256, 0, stream>>>(h);
    p4_kernel<<<256, 256, 0, stream>>>(h);
    fin_kernel<<<64, 256, 0, stream>>>(h);
}

// Round 9
// 209.587 us; speedup vs baseline: 1.8745x; 1.8745x over previous
//
#include <hip/hip_runtime.h>

// obj = (99*sum_t ||c_t||^2 + ||sum_t c_t||^2)/100, c_0 = D_F,
// c_{k+1} = E_k = C_F A_F^k B_F - C A^k B, B = eye(256,128), k=0..7.
//
// POWER-DOUBLING dataflow (verified absmax ~0 rounds 5-8):
//   P1: AF2=AF*AF, G1=CF*AF, A2=A*A, H1=C*A (+copies G0=CF, H0=C)
//   R1: resolve P1 fan-4 partials -> canonical AF2f, A2f, Gf[128:256], Hf[128:256]
//   P2: AF4=AF2*AF2, [G2;G3]=G[0:256]*AF2, A4, [H2;H3]      (fan-2 partials)
//   P3: [G4..G7]=G[0:512]*AF4, [H4..H7]=H[0:512]*A4          (fan-2 partials;
//       resolves P2 partials during Q/B staging)
//   P4: Ep = G*BF - H[:,:128]                                (fan-4 partials;
//       region-dispatched Q/H resolve)
//   fin: E = sum Ep; S1=sum|E|^2, S2=|DF+sumE|^2, SD=|DF|^2; ticketed out.
// Round-8 post-mortem: global fp32 atomicAdd fan-in = uncached RMW at the
// coherence point -> 94 MB WRITE_SIZE, ~100 us/kernel. This revision keeps
// round-7's LDS-balanced inner loop (2x4-complex thread tile: 48 LDS-cyc vs
// 160 VALU-cyc per 2kk -> VALU-bound at 4 waves/CU) and gets grid occupancy
// via split-K with PARTIAL BUFFERS resolved during consumer staging (the
// round-1-proven fan-in: plain cached loads/stores, zero atomics).

struct Params {
    const float *AFr, *AFi, *Ar, *Ai, *BFr, *BFi, *CFr, *CFi, *Cr, *Ci, *DFr, *DFi;
    float2 *Gf, *Hf, *AF2f, *A2f;           // canonical fp32 complex
    float2 *AF2p, *G1p, *A2p, *H1p;         // P1 fan-4 partials
    float2 *AF4p, *G23p, *A4p, *H23p;       // P2 fan-2 partials
    float2 *G45p, *H45p;                    // P3 fan-2 partials
    float2 *Ep;                             // P4 fan-4 partials
    float *S1, *S2, *SD; unsigned int *tick; float *out;
};

__device__ __forceinline__ unsigned int pk_bf16(float r, float i) {
    unsigned int u;
    asm("v_cvt_pk_bf16_f32 %0, %1, %2" : "=v"(u) : "v"(r), "v"(i));
    return u;   // low16 = bf16(r), high16 = bf16(i)
}

__device__ __forceinline__ float block_reduce(float v, float* red, int tid) {
    red[tid] = v;
    __syncthreads();
    for (int off = 128; off > 0; off >>= 1) {
        if (tid < off) red[tid] += red[tid + off];
        __syncthreads();
    }
    float r = red[0];
    __syncthreads();
    return r;
}

// one complex MAC against a packed-bf16 word
#define CM(wd, ar, ai, o)                                              \
    { float br_ = __uint_as_float((wd) << 16);                         \
      float bi_ = __uint_as_float((wd) & 0xffff0000u);                 \
      acc[o]     += (ar) * br_ - (ai) * bi_;                           \
      acc[(o)+1] += (ar) * bi_ + (ai) * br_; }

// ---- GEMM: block tile 16 rows x 128 cols, K = NCH*32 from k0, chunked via
// LDS. Thread (w=tid>>6, hi=(tid>>5)&1, cc=tid&31) owns rows {4w+2hi,+1},
// cols {c0+4cc..+3}: acc[16]. Q rows qrow0.. from split r/i inputs (QSPLIT)
// or float2 buffer(s) QfA(+QfB partial pair, summed). B from split r/i
// inputs (BSPLIT, converted) or float2 buffer(s) BfA(+BfB), summed+converted.
template<int NCH, bool QSPLIT, bool BSPLIT>
__device__ __forceinline__ void gemmX(
    const float* __restrict__ Qr, const float* __restrict__ Qi,
    const float2* __restrict__ QfA, const float2* __restrict__ QfB, int Wq, int qrow0,
    const float* __restrict__ Br, const float* __restrict__ Bi,
    const float2* __restrict__ BfA, const float2* __restrict__ BfB, int Wb,
    int c0, int k0, unsigned int* sBu, float2* sQ, float* acc) {
    const int tid = threadIdx.x, cc = tid & 31;
    const int r0 = 4 * (tid >> 6) + 2 * ((tid >> 5) & 1);
    #pragma unroll 1
    for (int ch = 0; ch < NCH; ++ch) {
        if (ch) __syncthreads();             // prior chunk's readers done
        const int kb = k0 + ch * 32;
        if constexpr (BSPLIT) {              // 32 x 128: 1024 uint4 slots
            #pragma unroll
            for (int j = 0; j < 4; ++j) {
                int slot = tid + j * 256;
                int row = slot >> 5, cq = (slot & 31) << 2;
                int g = (kb + row) * Wb + c0 + cq;
                float4 vr = *(const float4*)&Br[g];
                float4 vi = *(const float4*)&Bi[g];
                *(uint4*)&sBu[(row << 7) + cq] = make_uint4(
                    pk_bf16(vr.x, vi.x), pk_bf16(vr.y, vi.y),
                    pk_bf16(vr.z, vi.z), pk_bf16(vr.w, vi.w));
            }
        } else {                             // 2048 float4 (2-complex) slots
            #pragma unroll
            for (int j = 0; j < 8; ++j) {
                int slot = tid + j * 256;
                int row = slot >> 6, c2 = (slot & 63) << 1;
                int g = (kb + row) * Wb + c0 + c2;
                float4 v = *(const float4*)&BfA[g];
                if (BfB) {
                    float4 v2 = *(const float4*)&BfB[g];
                    v.x += v2.x; v.y += v2.y; v.z += v2.z; v.w += v2.w;
                }
                *(uint2*)&sBu[(row << 7) + c2] =
                    make_uint2(pk_bf16(v.x, v.y), pk_bf16(v.z, v.w));
            }
        }
        {   // Q: 16 rows x 32 kk, row-major stride 34 (bank spread)
            int row = tid >> 4, k2 = (tid & 15) << 1;
            int g = (qrow0 + row) * Wq + kb + k2;
            float4 v;
            if constexpr (QSPLIT) {
                float2 r2 = *(const float2*)&Qr[g];
                float2 i2 = *(const float2*)&Qi[g];
                v = make_float4(r2.x, i2.x, r2.y, i2.y);
            } else {
                v = *(const float4*)&QfA[g];
                if (QfB) {
                    float4 v2 = *(const float4*)&QfB[g];
                    v.x += v2.x; v.y += v2.y; v.z += v2.z; v.w += v2.w;
                }
            }
            *(float4*)&sQ[row * 34 + k2] = v;
        }
        __syncthreads();
        #pragma unroll 4
        for (int kk = 0; kk < 32; kk += 2) {
            float4 qa = *(const float4*)&sQ[r0 * 34 + kk];
            float4 qb = *(const float4*)&sQ[(r0 + 1) * 34 + kk];
            uint4 b0 = *(const uint4*)&sBu[(kk << 7) + (cc << 2)];
            uint4 b1 = *(const uint4*)&sBu[((kk + 1) << 7) + (cc << 2)];
            CM(b0.x, qa.x, qa.y, 0)  CM(b0.y, qa.x, qa.y, 2)
            CM(b0.z, qa.x, qa.y, 4)  CM(b0.w, qa.x, qa.y, 6)
            CM(b0.x, qb.x, qb.y, 8)  CM(b0.y, qb.x, qb.y, 10)
            CM(b0.z, qb.x, qb.y, 12) CM(b0.w, qb.x, qb.y, 14)
            CM(b1.x, qa.z, qa.w, 0)  CM(b1.y, qa.z, qa.w, 2)
            CM(b1.z, qa.z, qa.w, 4)  CM(b1.w, qa.z, qa.w, 6)
            CM(b1.x, qb.z, qb.w, 8)  CM(b1.y, qb.z, qb.w, 10)
            CM(b1.z, qb.z, qb.w, 12) CM(b1.w, qb.z, qb.w, 14)
        }
    }
}

__device__ __forceinline__ void st2x4(float2* O, int W, int prow, int pc,
                                      const float* a) {
    *(float4*)&O[prow * W + pc]           = make_float4(a[0], a[1], a[2], a[3]);
    *(float4*)&O[prow * W + pc + 2]       = make_float4(a[4], a[5], a[6], a[7]);
    *(float4*)&O[(prow + 1) * W + pc]     = make_float4(a[8], a[9], a[10], a[11]);
    *(float4*)&O[(prow + 1) * W + pc + 2] = make_float4(a[12], a[13], a[14], a[15]);
}

#define TDEC const int tid = threadIdx.x;                                   \
             const int cc = tid & 31;                                       \
             const int r0 = 4 * (tid >> 6) + 2 * ((tid >> 5) & 1);          \
             const int pc = cc << 2

// ---------------- P1 (592): fan-4 partials + copies -------------------------
// [0,288): AF2 24rg x 3cs x 4kp   [288,384): G1 8x3x4
// [384,512): A2 16x2x4            [512,576): H1 8x2x4   [576,592): copies
__global__ __launch_bounds__(256, 3)
void p1_kernel(Params P) {
    __shared__ __align__(16) unsigned int sBu[32 * 128];  // 16 KB
    __shared__ __align__(16) float2 sQ[16 * 34];          // 4.25 KB
    const int b = blockIdx.x;
    TDEC;
    float acc[16] = {};
    if (b < 288) {
        int rg = b / 12, r = b - 12 * rg, cs = r >> 2, kp = r & 3;
        gemmX<3, true, true>(P.AFr, P.AFi, nullptr, nullptr, 384, rg * 16,
                             P.AFr, P.AFi, nullptr, nullptr, 384,
                             cs << 7, kp * 96, sBu, sQ, acc);
        st2x4(P.AF2p + kp * 147456, 384, rg * 16 + r0, (cs << 7) + pc, acc);
    } else if (b < 384) {
        int u = b - 288, rg = u / 12, r = u - 12 * rg, cs = r >> 2, kp = r & 3;
        gemmX<3, true, true>(P.CFr, P.CFi, nullptr, nullptr, 384, rg * 16,
                             P.AFr, P.AFi, nullptr, nullptr, 384,
                             cs << 7, kp * 96, sBu, sQ, acc);
        st2x4(P.G1p + kp * 49152, 384, rg * 16 + r0, (cs << 7) + pc, acc);
    } else if (b < 512) {
        int u = b - 384, rg = u >> 3, r = u & 7, cs = r >> 2, kp = r & 3;
        gemmX<2, true, true>(P.Ar, P.Ai, nullptr, nullptr, 256, rg * 16,
                             P.Ar, P.Ai, nullptr, nullptr, 256,
                             cs << 7, kp * 64, sBu, sQ, acc);
        st2x4(P.A2p + kp * 65536, 256, rg * 16 + r0, (cs << 7) + pc, acc);
    } else if (b < 576) {
        int u = b - 512, rg = u >> 3, r = u & 7, cs = r >> 2, kp = r & 3;
        gemmX<2, true, true>(P.Cr, P.Ci, nullptr, nullptr, 256, rg * 16,
                             P.Ar, P.Ai, nullptr, nullptr, 256,
                             cs << 7, kp * 64, sBu, sQ, acc);
        st2x4(P.H1p + kp * 32768, 256, rg * 16 + r0, (cs << 7) + pc, acc);
    } else {
        for (int i = (b - 576) * 256 + tid; i < 81920; i += 16 * 256) {
            if (i < 49152) P.Gf[i] = make_float2(P.CFr[i], P.CFi[i]);          // G0
            else { int j = i - 49152; P.Hf[j] = make_float2(P.Cr[j], P.Ci[j]); } // H0
        }
    }
}

// ---------------- R1 (1152): resolve P1 fan-4 -> canonical ------------------
__global__ __launch_bounds__(256)
void r1_kernel(Params P) {
    int idx = blockIdx.x * 256 + threadIdx.x;     // 294912 total, exact
    if (idx < 147456) {
        float2 a = P.AF2p[idx], b = P.AF2p[147456 + idx];
        float2 c = P.AF2p[294912 + idx], d = P.AF2p[442368 + idx];
        P.AF2f[idx] = make_float2(a.x + b.x + c.x + d.x, a.y + b.y + c.y + d.y);
    } else if (idx < 196608) {
        int j = idx - 147456;
        float2 a = P.G1p[j], b = P.G1p[49152 + j];
        float2 c = P.G1p[98304 + j], d = P.G1p[147456 + j];
        P.Gf[49152 + j] = make_float2(a.x + b.x + c.x + d.x, a.y + b.y + c.y + d.y);
    } else if (idx < 262144) {
        int j = idx - 196608;
        float2 a = P.A2p[j], b = P.A2p[65536 + j];
        float2 c = P.A2p[131072 + j], d = P.A2p[196608 + j];
        P.A2f[j] = make_float2(a.x + b.x + c.x + d.x, a.y + b.y + c.y + d.y);
    } else {
        int j = idx - 262144;
        float2 a = P.H1p[j], b = P.H1p[32768 + j];
        float2 c = P.H1p[65536 + j], d = P.H1p[98304 + j];
        P.Hf[32768 + j] = make_float2(a.x + b.x + c.x + d.x, a.y + b.y + c.y + d.y);
    }
}

// ---------------- P2 (368): fan-2 partials from canonical -------------------
// [0,144): AF4 24x3x2  [144,240): G23 16x3x2  [240,304): A4 16x2x2
// [304,368): H23 16x2x2
__global__ __launch_bounds__(256, 3)
void p2_kernel(Params P) {
    __shared__ __align__(16) unsigned int sBu[32 * 128];
    __shared__ __align__(16) float2 sQ[16 * 34];
    const int b = blockIdx.x;
    TDEC;
    float acc[16] = {};
    if (b < 144) {
        int rg = b / 6, r = b - 6 * rg, cs = r >> 1, kp = r & 1;
        gemmX<6, false, false>(nullptr, nullptr, P.AF2f, nullptr, 384, rg * 16,
                               nullptr, nullptr, P.AF2f, nullptr, 384,
                               cs << 7, kp * 192, sBu, sQ, acc);
        st2x4(P.AF4p + kp * 147456, 384, rg * 16 + r0, (cs << 7) + pc, acc);
    } else if (b < 240) {
        int u = b - 144, rg = u / 6, r = u - 6 * rg, cs = r >> 1, kp = r & 1;
        gemmX<6, false, false>(nullptr, nullptr, P.Gf, nullptr, 384, rg * 16,
                               nullptr, nullptr, P.AF2f, nullptr, 384,
                               cs << 7, kp * 192, sBu, sQ, acc);
        st2x4(P.G23p + kp * 98304, 384, rg * 16 + r0, (cs << 7) + pc, acc);
    } else if (b < 304) {
        int u = b - 240, rg = u >> 2, r = u & 3, cs = r >> 1, kp = r & 1;
        gemmX<4, false, false>(nullptr, nullptr, P.A2f, nullptr, 256, rg * 16,
                               nullptr, nullptr, P.A2f, nullptr, 256,
                               cs << 7, kp * 128, sBu, sQ, acc);
        st2x4(P.A4p + kp * 65536, 256, rg * 16 + r0, (cs << 7) + pc, acc);
    } else {
        int u = b - 304, rg = u >> 2, r = u & 3, cs = r >> 1, kp = r & 1;
        gemmX<4, false, false>(nullptr, nullptr, P.Hf, nullptr, 256, rg * 16,
                               nullptr, nullptr, P.A2f, nullptr, 256,
                               cs << 7, kp * 128, sBu, sQ, acc);
        st2x4(P.H23p + kp * 65536, 256, rg * 16 + r0, (cs << 7) + pc, acc);
    }
}

// ---------------- P3 (320): fan-2 partials; resolves P2 pairs in staging ----
// [0,192): G4567 32x3x2     [192,320): H4567 32x2x2
__global__ __launch_bounds__(256, 3)
void p3_kernel(Params P) {
    __shared__ __align__(16) unsigned int sBu[32 * 128];
    __shared__ __align__(16) float2 sQ[16 * 34];
    const int b = blockIdx.x;
    TDEC;
    float acc[16] = {};
    if (b < 192) {
        int rg = b / 6, r = b - 6 * rg, cs = r >> 1, kp = r & 1;   // rg 0..31
        const float2 *qA, *qB = nullptr; int q0;
        if (rg < 16) { qA = P.Gf; q0 = rg * 16; }
        else { qA = P.G23p; qB = P.G23p + 98304; q0 = rg * 16 - 256; }
        gemmX<6, false, false>(nullptr, nullptr, qA, qB, 384, q0,
                               nullptr, nullptr, P.AF4p, P.AF4p + 147456, 384,
                               cs << 7, kp * 192, sBu, sQ, acc);
        st2x4(P.G45p + kp * 196608, 384, rg * 16 + r0, (cs << 7) + pc, acc);
    } else {
        int u = b - 192, rg = u >> 2, r = u & 3, cs = r >> 1, kp = r & 1; // rg 0..31
        const float2 *qA, *qB = nullptr; int q0;
        if (rg < 16) { qA = P.Hf; q0 = rg * 16; }
        else { qA = P.H23p; qB = P.H23p + 65536; q0 = rg * 16 - 256; }
        gemmX<4, false, false>(nullptr, nullptr, qA, qB, 256, q0,
                               nullptr, nullptr, P.A4p, P.A4p + 65536, 256,
                               cs << 7, kp * 128, sBu, sQ, acc);
        st2x4(P.H45p + kp * 131072, 256, rg * 16 + r0, (cs << 7) + pc, acc);
    }
}

// ---------------- P4 (256): Ep fan-4; region-dispatched Q/H resolve ---------
// rg = b>>2 (0..63: E rows rg*16..+15), kp = b&3; kp==0 subtracts H.
__global__ __launch_bounds__(256, 3)
void p4_kernel(Params P) {
    __shared__ __align__(16) unsigned int sBu[32 * 128];
    __shared__ __align__(16) float2 sQ[16 * 34];
    const int b = blockIdx.x;
    TDEC;
    const int rg = b >> 2, kp = b & 3;
    const float2 *qA, *qB = nullptr; int q0;
    if (rg < 16)      { qA = P.Gf;   q0 = rg * 16; }
    else if (rg < 32) { qA = P.G23p; qB = P.G23p + 98304;  q0 = rg * 16 - 256; }
    else              { qA = P.G45p; qB = P.G45p + 196608; q0 = rg * 16 - 512; }
    float acc[16] = {};
    gemmX<3, false, true>(nullptr, nullptr, qA, qB, 384, q0,
                          P.BFr, P.BFi, nullptr, nullptr, 128,
                          0, kp * 96, sBu, sQ, acc);
    const int prow = rg * 16 + r0;
    if (kp == 0) {
        const float2 *hA, *hB = nullptr; int h0;
        if (rg < 16)      { hA = P.Hf;   h0 = prow; }
        else if (rg < 32) { hA = P.H23p; hB = P.H23p + 65536;  h0 = prow - 256; }
        else              { hA = P.H45p; hB = P.H45p + 131072; h0 = prow - 512; }
        #pragma unroll
        for (int rr = 0; rr < 2; ++rr) {
            float* a = acc + 8 * rr;
            const float2* hrow = hA + (h0 + rr) * 256;
            float4 x0 = *(const float4*)&hrow[pc];
            float4 x1 = *(const float4*)&hrow[pc + 2];
            if (hB) {
                const float2* hrow2 = hB + (h0 + rr) * 256;
                float4 y0 = *(const float4*)&hrow2[pc];
                float4 y1 = *(const float4*)&hrow2[pc + 2];
                x0.x += y0.x; x0.y += y0.y; x0.z += y0.z; x0.w += y0.w;
                x1.x += y1.x; x1.y += y1.y; x1.z += y1.z; x1.w += y1.w;
            }
            a[0] -= x0.x; a[1] -= x0.y; a[2] -= x0.z; a[3] -= x0.w;
            a[4] -= x1.x; a[5] -= x1.y; a[6] -= x1.z; a[7] -= x1.w;
        }
    }
    st2x4(P.Ep + kp * 131072, 128, prow, pc, acc);
}

// ---------------- fin (64): resolve Ep, reductions, ticketed out ------------
__global__ __launch_bounds__(256)
void fin_kernel(Params P) {
    __shared__ float red[256];
    __shared__ int lastf;
    const int b = blockIdx.x, tid = threadIdx.x;
    const int idx = (b << 8) + tid;            // 0..16383 = p*128 + m
    const int p = idx >> 7, m = idx & 127;
    float dr = P.DFr[idx], di = P.DFi[idx];
    float s1 = 0.f, smr = dr, smi = di;
    #pragma unroll
    for (int k = 0; k < 8; ++k) {
        int ei = ((k << 7) + p) * 128 + m;
        float2 e0 = P.Ep[ei], e1 = P.Ep[131072 + ei];
        float2 e2 = P.Ep[262144 + ei], e3 = P.Ep[393216 + ei];
        float ex = e0.x + e1.x + e2.x + e3.x;
        float ey = e0.y + e1.y + e2.y + e3.y;
        s1 += ex * ex + ey * ey;
        smr += ex; smi += ey;
    }
    float s2 = smr * smr + smi * smi;
    float sd = dr * dr + di * di;
    float t = block_reduce(s1, red, tid);
    if (tid == 0) atomicAdd(P.S1, t);
    t = block_reduce(s2, red, tid);
    if (tid == 0) atomicAdd(P.S2, t);
    t = block_reduce(sd, red, tid);
    if (tid == 0) atomicAdd(P.SD, t);
    __syncthreads();   // drains this block's atomics before the ticket
    if (tid == 0) lastf = (atomicAdd(P.tick, 1u) == 63u) ? 1 : 0;
    __syncthreads();
    if (lastf && tid == 0) {
        float s1g = atomicAdd(P.S1, 0.f);
        float s2g = atomicAdd(P.S2, 0.f);
        float sdg = atomicAdd(P.SD, 0.f);
        P.out[0] = (99.0f * (s1g + sdg) + s2g) / 100.0f;
    }
}

extern "C" void kernel_launch(void* const* d_in, const int* in_sizes, int n_in,
                              void* d_out, int out_size, void* d_ws, size_t ws_size,
                              hipStream_t stream) {
    (void)in_sizes; (void)n_in; (void)out_size; (void)ws_size;
    char* ws = (char*)d_ws;
    Params h;
    h.Cr  = (const float*)d_in[0];
    h.Ci  = (const float*)d_in[1];
    h.Ar  = (const float*)d_in[2];
    h.Ai  = (const float*)d_in[3];
    h.AFr = (const float*)d_in[4];
    h.AFi = (const float*)d_in[5];
    h.BFr = (const float*)d_in[6];
    h.BFi = (const float*)d_in[7];
    h.CFr = (const float*)d_in[8];
    h.CFi = (const float*)d_in[9];
    h.DFr = (const float*)d_in[10];
    h.DFi = (const float*)d_in[11];
    h.Gf   = (float2*)(ws + 0);              // rows 0-255 used: 3145728 B resv
    h.Hf   = (float2*)(ws + 3145728);        // 2097152 -> 5242880
    h.AF2f = (float2*)(ws + 5242880);        // 1179648 -> 6422528
    h.A2f  = (float2*)(ws + 6422528);        // 524288  -> 6946816
    h.AF2p = (float2*)(ws + 6946816);        // 4x1179648 -> 11665408
    h.G1p  = (float2*)(ws + 11665408);       // 4x393216  -> 13238272
    h.A2p  = (float2*)(ws + 13238272);       // 4x524288  -> 15335424
    h.H1p  = (float2*)(ws + 15335424);       // 4x262144  -> 16384000
    h.AF4p = (float2*)(ws + 16384000);       // 2x1179648 -> 18743296
    h.G23p = (float2*)(ws + 18743296);       // 2x786432  -> 20316160
    h.A4p  = (float2*)(ws + 20316160);       // 2x524288  -> 21364736
    h.H23p = (float2*)(ws + 21364736);       // 2x524288  -> 22413312
    h.G45p = (float2*)(ws + 22413312);       // 2x1572864 -> 25559040
    h.H45p = (float2*)(ws + 25559040);       // 2x1048576 -> 27656192
    h.Ep   = (float2*)(ws + 27656192);       // 4x1048576 -> 31850496
    h.S1   = (float*)(ws + 31850496);
    h.S2   = (float*)(ws + 31850500);
    h.SD   = (float*)(ws + 31850504);
    h.tick = (unsigned int*)(ws + 31850508);
    h.out  = (float*)d_out;

    hipMemsetAsync(ws + 31850496, 0, 16, stream);   // S1,S2,SD,tick only
    p1_kernel<<<592, 256, 0, stream>>>(h);
    r1_kernel<<<1152, 256, 0, stream>>>(h);
    p2_kernel<<<368, 256, 0, stream>>>(h);
    p3_kernel<<<320, 256, 0, stream>>>(h);
    p4_kernel<<<256, 256, 0, stream>>>(h);
    fin_kernel<<<64, 256, 0, stream>>>(h);
}